// Round 6
// baseline (185.946 us; speedup 1.0000x reference)
//
#include <hip/hip_runtime.h>
#include <hip/hip_bf16.h>
#include <cstdint>
#include <cstddef>

typedef __attribute__((ext_vector_type(8))) _Float16 half8;
typedef __attribute__((ext_vector_type(4))) float f32x4;
typedef __attribute__((ext_vector_type(8))) unsigned short ushort8v;
typedef __attribute__((ext_vector_type(4))) unsigned short ushort4v;

__device__ __forceinline__ unsigned short f2h_bits(float x) {
  _Float16 h = (_Float16)x;
  union { _Float16 h; unsigned short u; } cv; cv.h = h; return cv.u;
}

__device__ __forceinline__ void barrier_raw() {
  asm volatile("" ::: "memory");
  __builtin_amdgcn_s_barrier();
  asm volatile("" ::: "memory");
}
template<int N> __device__ __forceinline__ void vmw() {
  static_assert(N == 0 || N == 3 || N == 4, "unsupported vmcnt");
  if constexpr (N == 0) asm volatile("s_waitcnt vmcnt(0)" ::: "memory");
  if constexpr (N == 3) asm volatile("s_waitcnt vmcnt(3)" ::: "memory");
  if constexpr (N == 4) asm volatile("s_waitcnt vmcnt(4)" ::: "memory");
}
__device__ __forceinline__ void lgkm0() {
  asm volatile("s_waitcnt lgkmcnt(0)" ::: "memory");
}

// ---------------- prep kernels (verified rounds 1-5) ----------------

__global__ __launch_bounds__(256) void k_f32_to_f16(const float* __restrict__ src,
                                                    unsigned short* __restrict__ dst, int n4) {
  int i = blockIdx.x * 256 + threadIdx.x;
  if (i >= n4) return;
  float4 v = ((const float4*)src)[i];
  ushort4v o;
  o[0] = f2h_bits(v.x); o[1] = f2h_bits(v.y); o[2] = f2h_bits(v.z); o[3] = f2h_bits(v.w);
  ((ushort4v*)dst)[i] = o;
}

__global__ __launch_bounds__(256) void k_transpose_f16(const float* __restrict__ W,
                                                       unsigned short* __restrict__ Wt,
                                                       int Kd, int N) {
  int tid = blockIdx.x * 256 + threadIdx.x;
  int total = (Kd >> 3) * N;
  if (tid >= total) return;
  int kc = tid / N;
  int n  = tid - kc * N;
  int k0 = kc << 3;
  ushort8v o;
#pragma unroll
  for (int j = 0; j < 8; ++j) o[j] = f2h_bits(W[(size_t)(k0 + j) * N + n]);
  *(ushort8v*)(&Wt[(size_t)n * Kd + k0]) = o;
}

__global__ __launch_bounds__(256) void k_build_head(
    const float* __restrict__ Wmu, const float* __restrict__ Wt,
    const float* __restrict__ Wpi,
    const float* __restrict__ bmu, const float* __restrict__ bt,
    const float* __restrict__ bpi,
    unsigned short* __restrict__ whd, float* __restrict__ bhd)
{
  int tid = blockIdx.x * 256 + threadIdx.x;
  if (tid >= 2304 * 64) return;
  int r  = tid >> 6;
  int d0 = (tid & 63) << 3;

  const float* src = nullptr; int stride = 0;
  if (r < 128) { src = Wmu + r; stride = 128; }
  else if (r < 2176) {
    int rU = r - 128, k = rU >> 8, i = (rU >> 4) & 15, j = rU & 15;
    if (j <= i) { src = Wt + k * 136 + ((i * (i + 1)) >> 1) + j; stride = 1088; }
  } else if (r < 2184) { src = Wpi + (r - 2176); stride = 8; }

  ushort8v o;
#pragma unroll
  for (int jj = 0; jj < 8; ++jj)
    o[jj] = src ? f2h_bits(src[(size_t)(d0 + jj) * stride]) : (unsigned short)0;
  *(ushort8v*)(&whd[(size_t)r * 512 + d0]) = o;

  if (d0 == 0) {
    float b = 0.f;
    if (r < 128) b = bmu[r];
    else if (r < 2176) {
      int rU = r - 128, k = rU >> 8, i = (rU >> 4) & 15, j = rU & 15;
      if (j <= i) b = bt[k * 136 + ((i * (i + 1)) >> 1) + j];
    } else if (r < 2184) b = bpi[r - 2176];
    bhd[r] = b;
  }
}

// ---- shared epilogue helpers (swapped-operand layout: row=l15-side, col=lk*4+reg) ----

__device__ __forceinline__ void epi_relu_h(const f32x4& a, const float* bias, int col0,
                                           unsigned short* Hout, size_t row, int N) {
  float4 b4 = *(const float4*)&bias[col0];
  ushort4v o;
  float v0 = a[0] + b4.x; o[0] = f2h_bits(v0 > 0.f ? v0 : 0.f);
  float v1 = a[1] + b4.y; o[1] = f2h_bits(v1 > 0.f ? v1 : 0.f);
  float v2 = a[2] + b4.z; o[2] = f2h_bits(v2 > 0.f ? v2 : 0.f);
  float v3 = a[3] + b4.w; o[3] = f2h_bits(v3 > 0.f ? v3 : 0.f);
  *(ushort4v*)&Hout[row * N + col0] = o;
}

__device__ __forceinline__ void epi_head(const f32x4& a, const float* bias, int col0,
                                         size_t row, float* out_pi, float* out_mu,
                                         float* out_tril) {
  if (col0 >= 2184) return;   // pad
  float4 b4 = *(const float4*)&bias[col0];
  float v[4] = { a[0] + b4.x, a[1] + b4.y, a[2] + b4.z, a[3] + b4.w };
  if (col0 < 128) {
    *(float4*)&out_mu[row * 128 + col0] = make_float4(v[0], v[1], v[2], v[3]);
  } else if (col0 < 2176) {
    const int cc0 = col0 - 128;
    const int i   = (cc0 >> 4) & 15;
    const int j0  = cc0 & 15;
#pragma unroll
    for (int r = 0; r < 4; ++r) if (j0 + r == i) v[r] = expf(v[r]);
    *(float4*)&out_tril[row * 2048 + cc0] = make_float4(v[0], v[1], v[2], v[3]);
  } else {
    // pi: lanes lk=0 hold cols 2176-79, lk=1 hold 2180-83 for the same row (lane^16)
    float m4 = fmaxf(fmaxf(v[0], v[1]), fmaxf(v[2], v[3]));
    float mx = fmaxf(m4, __shfl_xor(m4, 16));
    float e[4], s4 = 0.f;
#pragma unroll
    for (int r = 0; r < 4; ++r) { e[r] = expf(v[r] - mx); s4 += e[r]; }
    float sm = s4 + __shfl_xor(s4, 16);
    *(float4*)&out_pi[row * 8 + (col0 - 2176)] =
        make_float4(e[0] / sm, e[1] / sm, e[2] / sm, e[3] / sm);
  }
}

// -------- 3-buffer counted-vmcnt 128x128 GEMM: 4 waves, BK=32, T2-swizzled --------
// Pipeline: at step t, stage tile t+2 (4 loads/thread) into buf (t+2)%3; compute
// tile t from buf t%3; then vmcnt(4) [retires in issue order -> tile t+1's 4 loads
// done, t+2's may remain in flight] + s_barrier. Steady state never drains vmcnt(0).
// T2 swizzle identical to verified 8p kernel: chunk cl stored at cl ^ ((row>>1)&3)
// via pre-swizzled GLOBAL source + linear LDS dest; read offset xo.

template<int EPI>
__global__ __launch_bounds__(256) void k_gemm3b(
    const unsigned short* __restrict__ A,
    const unsigned short* __restrict__ Bt,
    int Kd, int N, int nNb,
    const float* __restrict__ bias,
    unsigned short* __restrict__ Hout,
    float* __restrict__ out_pi,
    float* __restrict__ out_mu,
    float* __restrict__ out_tril)
{
  __shared__ unsigned short Ald[3][128 * 32];
  __shared__ unsigned short Bld[3][128 * 32];

  const int tid  = threadIdx.x;
  const int lane = tid & 63;
  const int wv   = tid >> 6;
  const int wr   = wv >> 1;
  const int wc   = wv & 1;
  const int l15  = lane & 15;
  const int lk   = lane >> 4;

  const int cpx = gridDim.x >> 3;
  const int bid = blockIdx.x;
  const int swz = (bid & 7) * cpx + (bid >> 3);
  const int bm  = (swz / nNb) << 7;
  const int bn  = (swz % nNb) << 7;

  f32x4 acc[4][4] = {};

  const unsigned short* aBase = A  + (size_t)bm * Kd;
  const unsigned short* bBase = Bt + (size_t)bn * Kd;

  // read-side swizzled chunk offset (same proof as 8p kernel: (row>>1)&3 = (l15>>1)&3)
  const int xo = ((lk ^ ((l15 >> 1) & 3)) << 3);

  auto stage = [&](int bb, int kt) {
    const int k0 = kt << 5;
#pragma unroll
    for (int i = 0; i < 2; ++i) {
      const int cbase = (wv << 6) + (i << 8);   // wave-uniform 16B-chunk base, 512 total
      const int c_    = cbase + lane;
      const int row   = c_ >> 2;
      const int sc    = (((c_ & 3) ^ ((c_ >> 3) & 3)) << 3);  // pre-swizzled source col
      __builtin_amdgcn_global_load_lds(
          (const __attribute__((address_space(1))) void*)(aBase + (size_t)row * Kd + k0 + sc),
          (__attribute__((address_space(3))) void*)(&Ald[bb][cbase << 3]),
          16, 0, 0);
      __builtin_amdgcn_global_load_lds(
          (const __attribute__((address_space(1))) void*)(bBase + (size_t)row * Kd + k0 + sc),
          (__attribute__((address_space(3))) void*)(&Bld[bb][cbase << 3]),
          16, 0, 0);
    }
  };

  const int nk = Kd >> 5;   // all call sites have nk >= 2
  stage(0, 0);
  stage(1, 1);
  vmw<4>();                 // 8 outstanding -> wait oldest 4 (tile 0) done
  barrier_raw();

  int i0 = 0, i1 = 1, i2 = 2;
  for (int kt = 0; kt < nk; ++kt) {
    if (kt + 2 < nk) stage(i2, kt + 2);   // overwrites buf of tile kt-1 (reads done @ bar kt-1)

    half8 af[4], bfr[4];
#pragma unroll
    for (int m = 0; m < 4; ++m)
      af[m]  = *(const half8*)&Ald[i0][((wr << 6) + (m << 4) + l15) * 32 + xo];
#pragma unroll
    for (int n = 0; n < 4; ++n)
      bfr[n] = *(const half8*)&Bld[i0][((wc << 6) + (n << 4) + l15) * 32 + xo];

    __builtin_amdgcn_s_setprio(1);
#pragma unroll
    for (int m = 0; m < 4; ++m)
#pragma unroll
      for (int n = 0; n < 4; ++n)   // SWAPPED operands: lane holds 4 consecutive cols
        acc[m][n] = __builtin_amdgcn_mfma_f32_16x16x32_f16(bfr[n], af[m], acc[m][n], 0, 0, 0);
    __builtin_amdgcn_s_setprio(0);

    if (kt + 1 < nk) {
      if (kt + 2 < nk) vmw<4>();   // tile kt+1's loads done; kt+2's batch stays in flight
      else             vmw<0>();   // no younger batch to hide behind -> full drain
      barrier_raw();
    }
    const int t = i0; i0 = i1; i1 = i2; i2 = t;
  }

  // swapped layout: row = bm + wr*64 + m*16 + l15 ; col0 = bn + wc*64 + n*16 + lk*4
#pragma unroll
  for (int m = 0; m < 4; ++m) {
    const size_t row = bm + (wr << 6) + (m << 4) + l15;
#pragma unroll
    for (int n = 0; n < 4; ++n) {
      const int col0 = bn + (wc << 6) + (n << 4) + (lk << 2);
      if (EPI == 0) epi_relu_h(acc[m][n], bias, col0, Hout, row, N);
      else          epi_head(acc[m][n], bias, col0, row, out_pi, out_mu, out_tril);
    }
  }
}

// -------- 8-phase counted-vmcnt GEMM (round-4/5 verified), swapped epilogue --------

template<int NH, int M_rep>
__device__ __forceinline__ void mfma_phase(const half8* af, const half8* bf,
                                           f32x4 (*acc)[4]) {
  __builtin_amdgcn_s_setprio(1);
#pragma unroll
  for (int m = 0; m < M_rep; ++m) {   // SWAPPED operands
    acc[m][NH * 2 + 0] = __builtin_amdgcn_mfma_f32_16x16x32_f16(bf[0], af[m], acc[m][NH * 2 + 0], 0, 0, 0);
    acc[m][NH * 2 + 1] = __builtin_amdgcn_mfma_f32_16x16x32_f16(bf[1], af[m], acc[m][NH * 2 + 1], 0, 0, 0);
  }
  __builtin_amdgcn_s_setprio(0);
}

template<int BM, int BN>
__global__ __launch_bounds__(512) void k_gemm8p(
    const unsigned short* __restrict__ A,
    const unsigned short* __restrict__ Bt,
    int Kd, int N, int nNb,
    const float* __restrict__ bias,
    unsigned short* __restrict__ Hout)
{
  constexpr int M_rep = BM / 32;
  constexpr int A_LD  = BM / 128;
  constexpr int B_LD  = BN / 128;
  constexpr int WN    = A_LD + B_LD;

  __shared__ unsigned short Ald[2][2][BM * 32];
  __shared__ unsigned short Bld[2][2][BN * 32];

  const int tid  = threadIdx.x;
  const int lane = tid & 63;
  const int wid  = tid >> 6;
  const int wm   = wid >> 2;
  const int wn   = wid & 3;
  const int l15  = lane & 15;
  const int lk   = lane >> 4;

  const int cpx = gridDim.x >> 3;
  const int bid = blockIdx.x;
  const int swz = (bid & 7) * cpx + (bid >> 3);
  const int bm  = (swz / nNb) * BM;
  const int bn  = (swz % nNb) * BN;

  const unsigned short* aBase = A  + (size_t)bm * Kd;
  const unsigned short* bBase = Bt + (size_t)bn * Kd;

  f32x4 acc[M_rep][4] = {};

  const int xo   = ((lk ^ ((l15 >> 1) & 3)) << 3);
  const int rowA = wm * (BM / 2) + l15;
  const int colB = wn * 64 + l15;

  auto stageA = [&](int bb, int h, int k0) {
#pragma unroll
    for (int i = 0; i < A_LD; ++i) {
      const int cbase = (wid << 6) + (i << 9);
      const int c_    = cbase + lane;
      const int row   = c_ >> 2;
      const int sc    = (((c_ & 3) ^ ((c_ >> 3) & 3)) << 3);
      __builtin_amdgcn_global_load_lds(
          (const __attribute__((address_space(1))) void*)(aBase + (size_t)row * Kd + k0 + h * 32 + sc),
          (__attribute__((address_space(3))) void*)(&Ald[bb][h][(size_t)cbase << 3]),
          16, 0, 0);
    }
  };
  auto stageB = [&](int bb, int h, int k0) {
#pragma unroll
    for (int i = 0; i < B_LD; ++i) {
      const int cbase = (wid << 6) + (i << 9);
      const int c_    = cbase + lane;
      const int row   = c_ >> 2;
      const int sc    = (((c_ & 3) ^ ((c_ >> 3) & 3)) << 3);
      __builtin_amdgcn_global_load_lds(
          (const __attribute__((address_space(1))) void*)(bBase + (size_t)row * Kd + k0 + h * 32 + sc),
          (__attribute__((address_space(3))) void*)(&Bld[bb][h][(size_t)cbase << 3]),
          16, 0, 0);
    }
  };

#define RD_A(kk)                                                                 \
  {                                                                              \
    _Pragma("unroll")                                                            \
    for (int m = 0; m < M_rep; ++m)                                              \
      af[m] = *(const half8*)&Ald[cur][kk][(size_t)(rowA + m * 16) * 32 + xo];   \
  }
#define RD_B(kk, nh)                                                             \
  {                                                                              \
    _Pragma("unroll")                                                            \
    for (int n2 = 0; n2 < 2; ++n2)                                               \
      bf[n2] = *(const half8*)&Bld[cur][kk][(size_t)(colB + ((nh) * 2 + n2) * 16) * 32 + xo]; \
  }

  const int nk = Kd >> 6;
  stageA(0, 0, 0); stageB(0, 0, 0); stageA(0, 1, 0); stageB(0, 1, 0);
  vmw<WN>();
  barrier_raw();

  int cur = 0;
  for (int kt = 0; kt < nk; ++kt) {
    const bool pre = (kt + 1 < nk);
    const int  k0n = (kt + 1) << 6;
    half8 af[M_rep], bf[2];

    RD_A(0); RD_B(0, 0);
    if (pre) stageA(cur ^ 1, 0, k0n);
    barrier_raw(); lgkm0();
    mfma_phase<0, M_rep>(af, bf, acc);
    barrier_raw();

    RD_B(0, 1);
    if (pre) stageB(cur ^ 1, 0, k0n);
    barrier_raw(); lgkm0();
    mfma_phase<1, M_rep>(af, bf, acc);
    if (pre) vmw<WN>(); else vmw<0>();
    barrier_raw();

    RD_A(1); RD_B(1, 0);
    if (pre) stageA(cur ^ 1, 1, k0n);
    barrier_raw(); lgkm0();
    mfma_phase<0, M_rep>(af, bf, acc);
    barrier_raw();

    RD_B(1, 1);
    if (pre) stageB(cur ^ 1, 1, k0n);
    barrier_raw(); lgkm0();
    mfma_phase<1, M_rep>(af, bf, acc);
    if (pre) vmw<WN>();
    barrier_raw();

    cur ^= 1;
  }
#undef RD_A
#undef RD_B

  // swapped layout: row = bm + wm*(BM/2) + m*16 + l15 ; col0 = bn + wn*64 + n*16 + lk*4
#pragma unroll
  for (int m = 0; m < M_rep; ++m) {
    const size_t row = bm + wm * (BM / 2) + (m << 4) + l15;
#pragma unroll
    for (int n = 0; n < 4; ++n) {
      const int col0 = bn + wn * 64 + (n << 4) + (lk << 2);
      epi_relu_h(acc[m][n], bias, col0, Hout, row, N);
    }
  }
}

// ---------------- launch ----------------

extern "C" void kernel_launch(void* const* d_in, const int* in_sizes, int n_in,
                              void* d_out, int out_size, void* d_ws, size_t ws_size,
                              hipStream_t stream)
{
  const float* x   = (const float*)d_in[0];
  const float* W0  = (const float*)d_in[1];
  const float* b0  = (const float*)d_in[2];
  const float* W1  = (const float*)d_in[3];
  const float* b1  = (const float*)d_in[4];
  const float* W2  = (const float*)d_in[5];
  const float* b2  = (const float*)d_in[6];
  const float* Wpi = (const float*)d_in[7];
  const float* bpi = (const float*)d_in[8];
  const float* Wmu = (const float*)d_in[9];
  const float* bmu = (const float*)d_in[10];
  const float* Wt  = (const float*)d_in[11];
  const float* bt  = (const float*)d_in[12];

  char* ws = (char*)d_ws;
  unsigned short* xh  = (unsigned short*)(ws);             //  8,388,608 B
  unsigned short* h0  = (unsigned short*)(ws + 8388608);   // 33,554,432 B
  unsigned short* h1  = (unsigned short*)(ws + 41943040);  // 33,554,432 B
  unsigned short* h2  = (unsigned short*)(ws + 8388608);   // 16,777,216 B (aliases h0 — dead by then)
  unsigned short* w0b = (unsigned short*)(ws + 75497472);  //    524,288 B [1024][256]
  unsigned short* w1b = (unsigned short*)(ws + 76021760);  //  2,097,152 B [1024][1024]
  unsigned short* w2b = (unsigned short*)(ws + 78118912);  //  1,048,576 B [512][1024]
  unsigned short* whd = (unsigned short*)(ws + 79167488);  //  2,359,296 B [2304][512]
  float*          bhd = (float*)         (ws + 81526784);  //      9,216 B [2304]

  float* out_pi   = (float*)d_out;                // 131072
  float* out_mu   = (float*)d_out + 131072;       // 2097152
  float* out_tril = (float*)d_out + 2228224;      // 33554432

  // prep
  k_f32_to_f16<<<4096, 256, 0, stream>>>(x, xh, 1048576);
  k_transpose_f16<<<128, 256, 0, stream>>>(W0, w0b, 256, 1024);
  k_transpose_f16<<<512, 256, 0, stream>>>(W1, w1b, 1024, 1024);
  k_transpose_f16<<<256, 256, 0, stream>>>(W2, w2b, 1024, 512);
  k_build_head<<<576, 256, 0, stream>>>(Wmu, Wt, Wpi, bmu, bt, bpi, whd, bhd);

  // L0: short-K (256) -> 3-buffer 128^2 counted-vmcnt, 1024 blocks
  k_gemm3b<0><<<1024, 256, 0, stream>>>(xh, w0b, 256, 1024, 8, b0, h0,
                                        nullptr, nullptr, nullptr);
  // L1/L2: K=1024 -> 256-class 8-phase, 256 blocks (1/CU exact)
  k_gemm8p<256, 256><<<256, 512, 0, stream>>>(h0, w1b, 1024, 1024, 4, b1, h1);
  k_gemm8p<128, 256><<<256, 512, 0, stream>>>(h1, w2b, 1024, 512, 2, b2, h2);
  // head: K=512, write-heavy -> 3-buffer 128^2 counted-vmcnt, 2304 blocks
  k_gemm3b<1><<<2304, 256, 0, stream>>>(h2, whd, 512, 2304, 18, bhd, nullptr,
                                        out_pi, out_mu, out_tril);
}